// Round 2
// baseline (178.999 us; speedup 1.0000x reference)
//
#include <hip/hip_runtime.h>

// B=64, D=512 (ZD=E), L=8192, NL=1000, fp32.
// out[b,l] = s[b] * dot(zz[b,:], W_zlat[l,:])
//   zz = irm(z, Wz1/bz1, Wz2/bz2)   (real GEMM path, split-K atomics)
//   e-path collapsed algebraically:
//     u1 = w_proj + Wy2^T w_proj
//     u0 = u1 + Wy1^T u1
//     s[b] = sum_e (W_yemb[e,y[b]] + b_yemb[e]) * u0[e] + by1.u1 + by2.w_proj

#define BB 64
#define DD 512
#define LL 8192
#define NLBL 1000
#define PIT 68   // LDS pitch (floats): 68%32=4 -> consecutive rows land 4 banks apart

// ---------- matvec building block: vout = vin + W^T vin (one 32-wide e-chunk) ----------
__device__ __forceinline__ void matvec_block(int eblk, const float* __restrict__ W,
                                             const float* __restrict__ vin,
                                             float* __restrict__ vout) {
  __shared__ float vl[DD];
  __shared__ float red[256];
  int tid = threadIdx.x;
  vl[tid] = vin[tid];
  vl[tid + 256] = vin[tid + 256];
  __syncthreads();
  int el = tid & 31, jg = tid >> 5;
  int e = eblk * 32 + el;
  float acc = 0.f;
  for (int j = jg; j < DD; j += 8)
    acc += W[j * DD + e] * vl[j];     // lanes: 32 consecutive e -> coalesced
  red[tid] = acc;
  __syncthreads();
  if (tid < 32) {
    float s = vl[eblk * 32 + tid];
#pragma unroll
    for (int g = 0; g < 8; ++g) s += red[g * 32 + tid];
    vout[eblk * 32 + tid] = s;
  }
}

// ---------- residual layer GEMM block: O[b,j] += X[b,j]+bias[j]+dot (split-K atomic) ----
// grid slice: 128 blocks = 16 j-tiles(32) x 8 k-splits(64)
__device__ __forceinline__ void layer_gemm(int blk, const float* __restrict__ X,
                                           const float* __restrict__ W,
                                           const float* __restrict__ bias,
                                           float* __restrict__ O) {
  __shared__ __align__(16) float Xs[BB][PIT];
  __shared__ __align__(16) float Ws[32][PIT];
  int tid = threadIdx.x;
  int jt = blk >> 3, ks = blk & 7;
  int j0 = jt * 32, k0 = ks * 64;
#pragma unroll
  for (int i = 0; i < 4; ++i) {      // X tile 64x64
    int slot = tid + i * 256, row = slot >> 4, c4 = (slot & 15) * 4;
    *(float4*)&Xs[row][c4] = *(const float4*)&X[row * DD + k0 + c4];
  }
#pragma unroll
  for (int i = 0; i < 2; ++i) {      // W tile 32x64
    int slot = tid + i * 256, row = slot >> 4, c4 = (slot & 15) * 4;
    *(float4*)&Ws[row][c4] = *(const float4*)&W[(j0 + row) * DD + k0 + c4];
  }
  __syncthreads();
  int bl = tid & 15, jl = tid >> 4;  // b rows {bl+16i}, j rows {jl+16j}
  float acc[4][2] = {};
#pragma unroll
  for (int k = 0; k < 64; k += 4) {
    float4 xv[4], wv[2];
#pragma unroll
    for (int i = 0; i < 4; ++i) xv[i] = *(const float4*)&Xs[bl + 16 * i][k];
#pragma unroll
    for (int j = 0; j < 2; ++j) wv[j] = *(const float4*)&Ws[jl + 16 * j][k];
#pragma unroll
    for (int i = 0; i < 4; ++i)
#pragma unroll
      for (int j = 0; j < 2; ++j)
        acc[i][j] += xv[i].x * wv[j].x + xv[i].y * wv[j].y +
                     xv[i].z * wv[j].z + xv[i].w * wv[j].w;
  }
#pragma unroll
  for (int i = 0; i < 4; ++i) {
    int b = bl + 16 * i;
#pragma unroll
    for (int j = 0; j < 2; ++j) {
      int jj = j0 + jl + 16 * j;
      float v = acc[i][j];
      if (ks == 0) v += X[b * DD + jj] + bias[jj];   // residual+bias once
      atomicAdd(&O[b * DD + jj], v);
    }
  }
}

// ---------------- K0: u1 matvec + zero d_out + zero x1z/zz ----------------
__global__ __launch_bounds__(256) void k0(const float* __restrict__ Wy2,
                                          const float* __restrict__ w_proj,
                                          float* __restrict__ u1,
                                          float* __restrict__ out,
                                          float* __restrict__ zbase) {
  int blk = blockIdx.x, tid = threadIdx.x;
  if (blk < 16) {
    matvec_block(blk, Wy2, w_proj, u1);
  } else if (blk < 48) {             // zero out: 131072 float4 / 32 blocks
    float4* o4 = (float4*)out;
    int base = (blk - 16) * 4096 + tid;
#pragma unroll
    for (int i = 0; i < 16; ++i) o4[base + i * 256] = float4{0.f, 0.f, 0.f, 0.f};
  } else {                           // zero x1z+zz: 16384 float4 / 8 blocks
    float4* o4 = (float4*)zbase;
    int base = (blk - 48) * 2048 + tid;
#pragma unroll
    for (int i = 0; i < 8; ++i) o4[base + i * 256] = float4{0.f, 0.f, 0.f, 0.f};
  }
}

// ---------------- K1: z-layer1 + u0 matvec + d2 scalar ----------------
__global__ __launch_bounds__(256) void k1(const float* __restrict__ z,
                                          const float* __restrict__ Wz1,
                                          const float* __restrict__ bz1,
                                          float* __restrict__ x1z,
                                          const float* __restrict__ Wy1,
                                          const float* __restrict__ u1,
                                          float* __restrict__ u0,
                                          const float* __restrict__ by1,
                                          const float* __restrict__ by2,
                                          const float* __restrict__ w_proj,
                                          float* __restrict__ d2) {
  int blk = blockIdx.x;
  if (blk < 128) {
    layer_gemm(blk, z, Wz1, bz1, x1z);
  } else if (blk < 144) {
    matvec_block(blk - 128, Wy1, u1, u0);
  } else {
    __shared__ float red[256];
    int tid = threadIdx.x;
    float p = by1[tid] * u1[tid] + by2[tid] * w_proj[tid] +
              by1[tid + 256] * u1[tid + 256] + by2[tid + 256] * w_proj[tid + 256];
    red[tid] = p;
    __syncthreads();
    if (tid < 64) {
      float s = red[tid] + red[tid + 64] + red[tid + 128] + red[tid + 192];
#pragma unroll
      for (int d = 32; d; d >>= 1) s += __shfl_down(s, d, 64);
      if (tid == 0) d2[0] = s;
    }
  }
}

// ---------------- K2: z-layer2 + s[b] gather-dot ----------------
__global__ __launch_bounds__(256) void k2(const float* __restrict__ x1z,
                                          const float* __restrict__ Wz2,
                                          const float* __restrict__ bz2,
                                          float* __restrict__ zz,
                                          const float* __restrict__ W_yemb,
                                          const float* __restrict__ b_yemb,
                                          const int* __restrict__ y,
                                          const float* __restrict__ u0,
                                          const float* __restrict__ d2,
                                          float* __restrict__ sbv) {
  int blk = blockIdx.x;
  if (blk < 128) {
    layer_gemm(blk, x1z, Wz2, bz2, zz);
    return;
  }
  __shared__ float u0l[DD];
  int tid = threadIdx.x;
  u0l[tid] = u0[tid];
  u0l[tid + 256] = u0[tid + 256];
  __syncthreads();
  int bl = tid >> 5, el = tid & 31;
  int b = (blk - 128) * 8 + bl;
  int yb = y[b];
  float acc = 0.f;
  for (int e = el; e < DD; e += 32)
    acc += (W_yemb[(size_t)e * NLBL + yb] + b_yemb[e]) * u0l[e];
#pragma unroll
  for (int d = 16; d; d >>= 1) acc += __shfl_down(acc, d, 32);
  if (el == 0) sbv[b] = acc + d2[0];
}

// ---------------- K3: out[b,l] = s[b]*dot(zz[b],W[l]), split-K 8, 8bx8l tiles ------
// 256 blocks = 32 l-tiles(256) x 8 k-splits(64). 1 block/CU (87KB LDS).
__global__ __launch_bounds__(256) void k3(const float* __restrict__ zz,
                                          const float* __restrict__ W,
                                          const float* __restrict__ sbv,
                                          float* __restrict__ out) {
  __shared__ __align__(16) float Zs[BB][PIT];     // 17.4 KB
  __shared__ __align__(16) float Ws[256][PIT];    // 69.6 KB
  int tid = threadIdx.x;
  int blk = blockIdx.x;
  int lt = blk >> 3, ks = blk & 7;
  int l0 = lt * 256, k0 = ks * 64;
#pragma unroll
  for (int i = 0; i < 16; ++i) {     // W tile 256x64 = 4096 float4
    int slot = tid + i * 256, row = slot >> 4, c4 = (slot & 15) * 4;
    *(float4*)&Ws[row][c4] = *(const float4*)&W[(size_t)(l0 + row) * DD + k0 + c4];
  }
#pragma unroll
  for (int i = 0; i < 4; ++i) {      // zz tile 64x64 = 1024 float4
    int slot = tid + i * 256, row = slot >> 4, c4 = (slot & 15) * 4;
    *(float4*)&Zs[row][c4] = *(const float4*)&zz[row * DD + k0 + c4];
  }
  __syncthreads();
  int bg = tid & 7, lg = tid >> 3;   // b rows {bg+8i}, l rows {lg+32j}
  float acc[8][8] = {};
  for (int k = 0; k < 64; k += 4) {
    float4 zv[8], wv[8];
#pragma unroll
    for (int i = 0; i < 8; ++i) zv[i] = *(const float4*)&Zs[bg + 8 * i][k];
#pragma unroll
    for (int j = 0; j < 8; ++j) wv[j] = *(const float4*)&Ws[lg + 32 * j][k];
#pragma unroll
    for (int i = 0; i < 8; ++i)
#pragma unroll
      for (int j = 0; j < 8; ++j)
        acc[i][j] += zv[i].x * wv[j].x + zv[i].y * wv[j].y +
                     zv[i].z * wv[j].z + zv[i].w * wv[j].w;
  }
  float sv[8];
#pragma unroll
  for (int i = 0; i < 8; ++i) sv[i] = sbv[bg + 8 * i];
#pragma unroll
  for (int i = 0; i < 8; ++i) {
    size_t rowo = (size_t)(bg + 8 * i) * LL + l0 + lg;
#pragma unroll
    for (int j = 0; j < 8; ++j)
      atomicAdd(&out[rowo + 32 * j], sv[i] * acc[i][j]);
  }
}

extern "C" void kernel_launch(void* const* d_in, const int* in_sizes, int n_in,
                              void* d_out, int out_size, void* d_ws, size_t ws_size,
                              hipStream_t stream) {
  const float* z      = (const float*)d_in[0];
  const int*   y      = (const int*)  d_in[1];
  const float* W_yemb = (const float*)d_in[2];
  const float* b_yemb = (const float*)d_in[3];
  const float* Wy1    = (const float*)d_in[4];
  const float* by1    = (const float*)d_in[5];
  const float* Wy2    = (const float*)d_in[6];
  const float* by2    = (const float*)d_in[7];
  const float* Wz1    = (const float*)d_in[8];
  const float* bz1    = (const float*)d_in[9];
  const float* Wz2    = (const float*)d_in[10];
  const float* bz2    = (const float*)d_in[11];
  const float* W_zlat = (const float*)d_in[12];
  const float* w_proj = (const float*)d_in[13];

  float* ws  = (float*)d_ws;
  float* x1z = ws;           // [64*512] (atomic target, zeroed in k0)
  float* zz  = ws + 32768;   // [64*512] (atomic target, zeroed in k0)
  float* u1  = ws + 65536;   // [512]
  float* u0  = ws + 66048;   // [512]
  float* sb  = ws + 66560;   // [64]
  float* d2  = ws + 66624;   // [1]
  float* out = (float*)d_out;

  k0<<<56, 256, 0, stream>>>(Wy2, w_proj, u1, out, x1z);
  k1<<<145, 256, 0, stream>>>(z, Wz1, bz1, x1z, Wy1, u1, u0, by1, by2, w_proj, d2);
  k2<<<136, 256, 0, stream>>>(x1z, Wz2, bz2, zz, W_yemb, b_yemb, y, u0, d2, sb);
  k3<<<256, 256, 0, stream>>>(zz, W_zlat, sb, out);
}

// Round 3
// 159.962 us; speedup vs baseline: 1.1190x; 1.1190x over previous
//
#include <hip/hip_runtime.h>

// B=64, D=512 (ZD=E), L=8192, NL=1000, fp32. No atomics anywhere.
// out[b,l] = s[b] * dot(zz[b,:], W_zlat[l,:])
//   zz = irm(z, Wz1/bz1, Wz2/bz2)  via split-K partials + fused staging reduce
//   e-path collapsed: u1 = w_proj + Wy2^T w_proj; u0 = u1 + Wy1^T u1
//   s[b] = sum_e (W_yemb[e,y[b]]+b_yemb[e])*u0[e] + by1.u1 + by2.w_proj

#define BB 64
#define DD 512
#define LL 8192
#define NLBL 1000
#define PIT 68   // LDS pitch: rows 4 banks apart, 16B-aligned

// ---------- matvec: vout = vin + W^T vin (one 32-wide e-chunk) ----------
__device__ __forceinline__ void matvec_block(int eblk, const float* __restrict__ W,
                                             const float* __restrict__ vin,
                                             float* __restrict__ vout) {
  __shared__ float vl[DD];
  __shared__ float red[256];
  int tid = threadIdx.x;
  vl[tid] = vin[tid];
  vl[tid + 256] = vin[tid + 256];
  __syncthreads();
  int el = tid & 31, jg = tid >> 5;
  int e = eblk * 32 + el;
  float acc = 0.f;
  for (int j = jg; j < DD; j += 8)
    acc += W[j * DD + e] * vl[j];
  red[tid] = acc;
  __syncthreads();
  if (tid < 32) {
    float s = vl[eblk * 32 + tid];
#pragma unroll
    for (int g = 0; g < 8; ++g) s += red[g * 32 + tid];
    vout[eblk * 32 + tid] = s;
  }
}

// ---------- layer GEMM, split-K 8, plain partial stores ----------
// P[ks][b][j] ; ks==0 partial carries residual X[b,j] + bias[j].
// FIRST=1: X read directly from Xg. FIRST=0: X[b,k] = sum_s P1[s][b][k].
template <int FIRST>
__device__ __forceinline__ void layer_gemm(int blk, const float* __restrict__ Xg,
                                           const float* __restrict__ P1,
                                           const float* __restrict__ W,
                                           const float* __restrict__ bias,
                                           float* __restrict__ P) {
  __shared__ __align__(16) float Xs[BB][PIT];
  __shared__ __align__(16) float Ws[32][PIT];
  int tid = threadIdx.x;
  int jt = blk >> 3, ks = blk & 7;
  int j0 = jt * 32, k0 = ks * 64;
#pragma unroll
  for (int i = 0; i < 4; ++i) {      // X tile 64x64
    int slot = tid + i * 256, row = slot >> 4, c4 = (slot & 15) * 4;
    float4 v;
    if (FIRST) {
      v = *(const float4*)&Xg[row * DD + k0 + c4];
    } else {
      v = float4{0.f, 0.f, 0.f, 0.f};
#pragma unroll
      for (int s = 0; s < 8; ++s) {
        float4 p = *(const float4*)&P1[(s * BB + row) * DD + k0 + c4];
        v.x += p.x; v.y += p.y; v.z += p.z; v.w += p.w;
      }
    }
    *(float4*)&Xs[row][c4] = v;
  }
#pragma unroll
  for (int i = 0; i < 2; ++i) {      // W tile 32x64
    int slot = tid + i * 256, row = slot >> 4, c4 = (slot & 15) * 4;
    *(float4*)&Ws[row][c4] = *(const float4*)&W[(j0 + row) * DD + k0 + c4];
  }
  __syncthreads();
  int jl = tid & 15, bl = tid >> 4;  // j = j0+jl+16u, b = bl+16i
  float acc[4][2] = {};
#pragma unroll
  for (int k = 0; k < 64; k += 4) {
    float4 xv[4], wv[2];
#pragma unroll
    for (int i = 0; i < 4; ++i) xv[i] = *(const float4*)&Xs[bl + 16 * i][k];
#pragma unroll
    for (int u = 0; u < 2; ++u) wv[u] = *(const float4*)&Ws[jl + 16 * u][k];
#pragma unroll
    for (int i = 0; i < 4; ++i)
#pragma unroll
      for (int u = 0; u < 2; ++u)
        acc[i][u] += xv[i].x * wv[u].x + xv[i].y * wv[u].y +
                     xv[i].z * wv[u].z + xv[i].w * wv[u].w;
  }
#pragma unroll
  for (int i = 0; i < 4; ++i) {
    int b = bl + 16 * i;
#pragma unroll
    for (int u = 0; u < 2; ++u) {
      int jj = j0 + jl + 16 * u;
      float v = acc[i][u];
      if (ks == 0) {                 // fold residual + bias into partial 0
        float xr;
        if (FIRST) {
          xr = Xg[b * DD + jj];
        } else {
          xr = 0.f;
#pragma unroll
          for (int s = 0; s < 8; ++s) xr += P1[(s * BB + b) * DD + jj];
        }
        v += xr + bias[jj];
      }
      P[(ks * BB + b) * DD + jj] = v;   // 16-lane coalesced segments
    }
  }
}

// ---------------- K0: u1 matvec ----------------
__global__ __launch_bounds__(256) void k0(const float* __restrict__ Wy2,
                                          const float* __restrict__ w_proj,
                                          float* __restrict__ u1) {
  matvec_block(blockIdx.x, Wy2, w_proj, u1);
}

// ---------------- K1: z-layer1 partials + u0 matvec + d2 scalar ----------------
__global__ __launch_bounds__(256) void k1(const float* __restrict__ z,
                                          const float* __restrict__ Wz1,
                                          const float* __restrict__ bz1,
                                          float* __restrict__ P1,
                                          const float* __restrict__ Wy1,
                                          const float* __restrict__ u1,
                                          float* __restrict__ u0,
                                          const float* __restrict__ by1,
                                          const float* __restrict__ by2,
                                          const float* __restrict__ w_proj,
                                          float* __restrict__ d2) {
  int blk = blockIdx.x;
  if (blk < 128) {
    layer_gemm<1>(blk, z, nullptr, Wz1, bz1, P1);
  } else if (blk < 144) {
    matvec_block(blk - 128, Wy1, u1, u0);
  } else {
    __shared__ float red[256];
    int tid = threadIdx.x;
    float p = by1[tid] * u1[tid] + by2[tid] * w_proj[tid] +
              by1[tid + 256] * u1[tid + 256] + by2[tid + 256] * w_proj[tid + 256];
    red[tid] = p;
    __syncthreads();
    if (tid < 64) {
      float s = red[tid] + red[tid + 64] + red[tid + 128] + red[tid + 192];
#pragma unroll
      for (int d = 32; d; d >>= 1) s += __shfl_down(s, d, 64);
      if (tid == 0) d2[0] = s;
    }
  }
}

// ---------------- K2: z-layer2 partials + s[b] gather-dot ----------------
__global__ __launch_bounds__(256) void k2(const float* __restrict__ P1,
                                          const float* __restrict__ Wz2,
                                          const float* __restrict__ bz2,
                                          float* __restrict__ P2,
                                          const float* __restrict__ W_yemb,
                                          const float* __restrict__ b_yemb,
                                          const int* __restrict__ y,
                                          const float* __restrict__ u0,
                                          const float* __restrict__ d2,
                                          float* __restrict__ sbv) {
  int blk = blockIdx.x;
  if (blk < 128) {
    layer_gemm<0>(blk, nullptr, P1, Wz2, bz2, P2);
    return;
  }
  __shared__ float u0l[DD];
  int tid = threadIdx.x;
  u0l[tid] = u0[tid];
  u0l[tid + 256] = u0[tid + 256];
  __syncthreads();
  int bl = tid >> 5, el = tid & 31;
  int b = (blk - 128) * 8 + bl;
  int yb = y[b];
  float acc = 0.f;
  for (int e = el; e < DD; e += 32)
    acc += (W_yemb[(size_t)e * NLBL + yb] + b_yemb[e]) * u0l[e];
#pragma unroll
  for (int d = 16; d; d >>= 1) acc += __shfl_down(acc, d, 32);
  if (el == 0) sbv[b] = acc + d2[0];
}

// ---------------- K3: partials of zz @ W_zlat^T, split-K 8, 8b x 8l ----------
// 256 blocks = (lt = blk>>3: 32 l-tiles of 256) x (ks = blk&7: k-chunks of 64)
// zz staged as sum of 8 P2 partials. Partial out stored thread-ordered:
// P3[blk*16384 + (i*8+j)*256 + tid]  (lane-contiguous, coalesced)
__global__ __launch_bounds__(256) void k3(const float* __restrict__ P2,
                                          const float* __restrict__ W,
                                          float* __restrict__ P3) {
  __shared__ __align__(16) float Zs[BB][PIT];     // 17.4 KB
  __shared__ __align__(16) float Ws[256][PIT];    // 69.6 KB
  int tid = threadIdx.x;
  int blk = blockIdx.x;
  int lt = blk >> 3, ks = blk & 7;
  int l0 = lt * 256, k0 = ks * 64;
#pragma unroll
  for (int i = 0; i < 16; ++i) {     // W tile 256x64
    int slot = tid + i * 256, row = slot >> 4, c4 = (slot & 15) * 4;
    *(float4*)&Ws[row][c4] = *(const float4*)&W[(size_t)(l0 + row) * DD + k0 + c4];
  }
#pragma unroll
  for (int i = 0; i < 4; ++i) {      // zz tile 64x64 = sum of 8 partials
    int slot = tid + i * 256, row = slot >> 4, c4 = (slot & 15) * 4;
    float4 v = float4{0.f, 0.f, 0.f, 0.f};
#pragma unroll
    for (int s = 0; s < 8; ++s) {
      float4 p = *(const float4*)&P2[(s * BB + row) * DD + k0 + c4];
      v.x += p.x; v.y += p.y; v.z += p.z; v.w += p.w;
    }
    *(float4*)&Zs[row][c4] = v;
  }
  __syncthreads();
  int bg = tid & 7, lg = tid >> 3;   // b = bg+8i, l = l0+lg+32j
  float acc[8][8] = {};
  for (int k = 0; k < 64; k += 4) {
    float4 zv[8], wv[8];
#pragma unroll
    for (int i = 0; i < 8; ++i) zv[i] = *(const float4*)&Zs[bg + 8 * i][k];
#pragma unroll
    for (int j = 0; j < 8; ++j) wv[j] = *(const float4*)&Ws[lg + 32 * j][k];
#pragma unroll
    for (int i = 0; i < 8; ++i)
#pragma unroll
      for (int j = 0; j < 8; ++j)
        acc[i][j] += zv[i].x * wv[j].x + zv[i].y * wv[j].y +
                     zv[i].z * wv[j].z + zv[i].w * wv[j].w;
  }
  float* base = P3 + (size_t)blk * 16384 + tid;
#pragma unroll
  for (int i = 0; i < 8; ++i)
#pragma unroll
    for (int j = 0; j < 8; ++j)
      base[(i * 8 + j) * 256] = acc[i][j];
}

// ---------------- K4: reduce 8 k-splits, scale by s[b], coalesced out ---------
// 256 blocks = (lt = blk>>3) x (i = blk&7). Covers b in [8i, 8i+8), l-tile lt.
__global__ __launch_bounds__(256) void k4(const float* __restrict__ P3,
                                          const float* __restrict__ sbv,
                                          float* __restrict__ out) {
  __shared__ __align__(16) float T[8][264];
  int tid = threadIdx.x;
  int lt = blockIdx.x >> 3, i = blockIdx.x & 7;
  int bg = tid & 7, lg = tid >> 3;
  float sv = sbv[bg + 8 * i];
#pragma unroll
  for (int j = 0; j < 8; ++j) {
    float v = 0.f;
#pragma unroll
    for (int ks = 0; ks < 8; ++ks)
      v += P3[(size_t)(lt * 8 + ks) * 16384 + (i * 8 + j) * 256 + tid];
    T[bg][lg + 32 * j] = v * sv;
  }
  __syncthreads();
#pragma unroll
  for (int r = 0; r < 2; ++r) {      // 512 float4 slots: 8 rows x 64
    int slot = tid + r * 256;
    int row = slot >> 6, c4 = (slot & 63) * 4;
    float4 v = *(const float4*)&T[row][c4];
    *(float4*)&out[(size_t)(8 * i + row) * LL + lt * 256 + c4] = v;
  }
}

extern "C" void kernel_launch(void* const* d_in, const int* in_sizes, int n_in,
                              void* d_out, int out_size, void* d_ws, size_t ws_size,
                              hipStream_t stream) {
  const float* z      = (const float*)d_in[0];
  const int*   y      = (const int*)  d_in[1];
  const float* W_yemb = (const float*)d_in[2];
  const float* b_yemb = (const float*)d_in[3];
  const float* Wy1    = (const float*)d_in[4];
  const float* by1    = (const float*)d_in[5];
  const float* Wy2    = (const float*)d_in[6];
  const float* by2    = (const float*)d_in[7];
  const float* Wz1    = (const float*)d_in[8];
  const float* bz1    = (const float*)d_in[9];
  const float* Wz2    = (const float*)d_in[10];
  const float* bz2    = (const float*)d_in[11];
  const float* W_zlat = (const float*)d_in[12];
  const float* w_proj = (const float*)d_in[13];

  float* ws = (float*)d_ws;
  float* P1 = ws;                 // [8][64][512]   = 262144
  float* P2 = ws + 262144;        // [8][64][512]   = 262144
  float* P3 = ws + 524288;        // [256][64][256] = 4194304
  float* u1 = ws + 4718592;       // [512]
  float* u0 = ws + 4719104;       // [512]
  float* sb = ws + 4719616;       // [64]
  float* d2 = ws + 4719680;       // [1]
  float* out = (float*)d_out;

  k0<<<16, 256, 0, stream>>>(Wy2, w_proj, u1);
  k1<<<145, 256, 0, stream>>>(z, Wz1, bz1, P1, Wy1, u1, u0, by1, by2, w_proj, d2);
  k2<<<136, 256, 0, stream>>>(P1, Wz2, bz2, P2, W_yemb, b_yemb, y, u0, d2, sb);
  k3<<<256, 256, 0, stream>>>(P2, W_zlat, P3);
  k4<<<256, 256, 0, stream>>>(P3, sb, out);
}

// Round 4
// 156.067 us; speedup vs baseline: 1.1469x; 1.0250x over previous
//
#include <hip/hip_runtime.h>

// B=64, D=512 (ZD=E), L=8192, NL=1000, fp32. No atomics. 4 dispatches.
// out[b,l] = s[b] * dot(zz[b,:], W_zlat[l,:])
//   zz = irm(z, Wz1/bz1, Wz2/bz2)  via split-K-8 partials, re-summed during staging
//   e-path collapsed: u1 = w_proj + Wy2^T w_proj; u0 = u1 + Wy1^T u1
//   s[b] = sum_e (W_yemb[e,y[b]]+b_yemb[e])*u0[e] + by1.u1 + by2.w_proj
// Dispatch chain: kA(layer1->P1, u1) -> kB(layer2->P2, u0, d2)
//                 -> kC(GEMM->P3, s-gather) -> kD(reduce*s -> out)

#define BB 64
#define DD 512
#define LL 8192
#define NLBL 1000
#define PIT 68   // LDS pitch: rows 4 banks apart, 16B-aligned

// ---------- matvec: vout = vin + W^T vin (one 32-wide e-chunk) ----------
__device__ __forceinline__ void matvec_block(int eblk, const float* __restrict__ W,
                                             const float* __restrict__ vin,
                                             float* __restrict__ vout) {
  __shared__ float vl[DD];
  __shared__ float red[256];
  int tid = threadIdx.x;
  vl[tid] = vin[tid];
  vl[tid + 256] = vin[tid + 256];
  __syncthreads();
  int el = tid & 31, jg = tid >> 5;
  int e = eblk * 32 + el;
  float acc = 0.f;
  for (int j = jg; j < DD; j += 8)
    acc += W[j * DD + e] * vl[j];
  red[tid] = acc;
  __syncthreads();
  if (tid < 32) {
    float s = vl[eblk * 32 + tid];
#pragma unroll
    for (int g = 0; g < 8; ++g) s += red[g * 32 + tid];
    vout[eblk * 32 + tid] = s;
  }
}

// ---------- layer GEMM, split-K 8, plain partial stores ----------
// P[ks][b][j]; ks==0 partial carries residual X[b,j] + bias[j].
template <int FIRST>
__device__ __forceinline__ void layer_gemm(int blk, const float* __restrict__ Xg,
                                           const float* __restrict__ P1,
                                           const float* __restrict__ W,
                                           const float* __restrict__ bias,
                                           float* __restrict__ P) {
  __shared__ __align__(16) float Xs[BB][PIT];
  __shared__ __align__(16) float Ws[32][PIT];
  int tid = threadIdx.x;
  int jt = blk >> 3, ks = blk & 7;
  int j0 = jt * 32, k0 = ks * 64;
#pragma unroll
  for (int i = 0; i < 4; ++i) {      // X tile 64x64
    int slot = tid + i * 256, row = slot >> 4, c4 = (slot & 15) * 4;
    float4 v;
    if (FIRST) {
      v = *(const float4*)&Xg[row * DD + k0 + c4];
    } else {
      v = float4{0.f, 0.f, 0.f, 0.f};
#pragma unroll
      for (int s = 0; s < 8; ++s) {
        float4 p = *(const float4*)&P1[(s * BB + row) * DD + k0 + c4];
        v.x += p.x; v.y += p.y; v.z += p.z; v.w += p.w;
      }
    }
    *(float4*)&Xs[row][c4] = v;
  }
#pragma unroll
  for (int i = 0; i < 2; ++i) {      // W tile 32x64
    int slot = tid + i * 256, row = slot >> 4, c4 = (slot & 15) * 4;
    *(float4*)&Ws[row][c4] = *(const float4*)&W[(j0 + row) * DD + k0 + c4];
  }
  __syncthreads();
  int jl = tid & 15, bl = tid >> 4;  // j = j0+jl+16u, b = bl+16i
  float acc[4][2] = {};
#pragma unroll
  for (int k = 0; k < 64; k += 4) {
    float4 xv[4], wv[2];
#pragma unroll
    for (int i = 0; i < 4; ++i) xv[i] = *(const float4*)&Xs[bl + 16 * i][k];
#pragma unroll
    for (int u = 0; u < 2; ++u) wv[u] = *(const float4*)&Ws[jl + 16 * u][k];
#pragma unroll
    for (int i = 0; i < 4; ++i)
#pragma unroll
      for (int u = 0; u < 2; ++u)
        acc[i][u] += xv[i].x * wv[u].x + xv[i].y * wv[u].y +
                     xv[i].z * wv[u].z + xv[i].w * wv[u].w;
  }
#pragma unroll
  for (int i = 0; i < 4; ++i) {
    int b = bl + 16 * i;
#pragma unroll
    for (int u = 0; u < 2; ++u) {
      int jj = j0 + jl + 16 * u;
      float v = acc[i][u];
      if (ks == 0) {
        float xr;
        if (FIRST) {
          xr = Xg[b * DD + jj];
        } else {
          xr = 0.f;
#pragma unroll
          for (int s = 0; s < 8; ++s) xr += P1[(s * BB + b) * DD + jj];
        }
        v += xr + bias[jj];
      }
      P[(ks * BB + b) * DD + jj] = v;
    }
  }
}

// ---------------- kA: layer1 partials + u1 matvec ----------------
__global__ __launch_bounds__(256) void kA(const float* __restrict__ z,
                                          const float* __restrict__ Wz1,
                                          const float* __restrict__ bz1,
                                          float* __restrict__ P1,
                                          const float* __restrict__ Wy2,
                                          const float* __restrict__ w_proj,
                                          float* __restrict__ u1) {
  int blk = blockIdx.x;
  if (blk < 128) layer_gemm<1>(blk, z, nullptr, Wz1, bz1, P1);
  else           matvec_block(blk - 128, Wy2, w_proj, u1);
}

// ---------------- kB: layer2 partials + u0 matvec + d2 scalar ----------------
__global__ __launch_bounds__(256) void kB(const float* __restrict__ P1,
                                          const float* __restrict__ Wz2,
                                          const float* __restrict__ bz2,
                                          float* __restrict__ P2,
                                          const float* __restrict__ Wy1,
                                          const float* __restrict__ u1,
                                          float* __restrict__ u0,
                                          const float* __restrict__ by1,
                                          const float* __restrict__ by2,
                                          const float* __restrict__ w_proj,
                                          float* __restrict__ d2) {
  int blk = blockIdx.x;
  if (blk < 128) {
    layer_gemm<0>(blk, nullptr, P1, Wz2, bz2, P2);
  } else if (blk < 144) {
    matvec_block(blk - 128, Wy1, u1, u0);
  } else {
    __shared__ float red[256];
    int tid = threadIdx.x;
    float p = by1[tid] * u1[tid] + by2[tid] * w_proj[tid] +
              by1[tid + 256] * u1[tid + 256] + by2[tid + 256] * w_proj[tid + 256];
    red[tid] = p;
    __syncthreads();
    if (tid < 64) {
      float s = red[tid] + red[tid + 64] + red[tid + 128] + red[tid + 192];
#pragma unroll
      for (int d = 32; d; d >>= 1) s += __shfl_down(s, d, 64);
      if (tid == 0) d2[0] = s;
    }
  }
}

// ---------------- kC: GEMM partials (split-K 8, 8b x 8l) + s[b] gather-dot ----
// GEMM blocks 0..255: ks = blk>>5 (k-chunk of 64), lt = blk&31 (l-tile of 256).
// XCD heuristic: blk%8 == lt%8, matching kD's reader for L2-resident P3.
// Blocks 256..263: s-gather.
__global__ __launch_bounds__(256) void kC(const float* __restrict__ P2,
                                          const float* __restrict__ W,
                                          float* __restrict__ P3,
                                          const float* __restrict__ W_yemb,
                                          const float* __restrict__ b_yemb,
                                          const int* __restrict__ y,
                                          const float* __restrict__ u0,
                                          const float* __restrict__ d2,
                                          float* __restrict__ sbv) {
  int blk = blockIdx.x;
  int tid = threadIdx.x;
  if (blk >= 256) {                  // ---- s-gather: 8 blocks x 8 batches ----
    __shared__ float u0l[DD];
    u0l[tid] = u0[tid];
    u0l[tid + 256] = u0[tid + 256];
    __syncthreads();
    int bl = tid >> 5, el = tid & 31;
    int b = (blk - 256) * 8 + bl;
    int yb = y[b];
    float acc = 0.f;
    for (int e = el; e < DD; e += 32)
      acc += (W_yemb[(size_t)e * NLBL + yb] + b_yemb[e]) * u0l[e];
#pragma unroll
    for (int d = 16; d; d >>= 1) acc += __shfl_down(acc, d, 32);
    if (el == 0) sbv[b] = acc + d2[0];
    return;
  }
  __shared__ __align__(16) float Zs[BB][PIT];     // 17.4 KB
  __shared__ __align__(16) float Ws[256][PIT];    // 69.6 KB
  int ks = blk >> 5, lt = blk & 31;
  int l0 = lt * 256, k0 = ks * 64;
  // issue W global loads first (registers), overlap latency with P2-sum staging
  float4 wreg[16];
#pragma unroll
  for (int i = 0; i < 16; ++i) {
    int slot = tid + i * 256, row = slot >> 4, c4 = (slot & 15) * 4;
    wreg[i] = *(const float4*)&W[(size_t)(l0 + row) * DD + k0 + c4];
  }
#pragma unroll
  for (int i = 0; i < 4; ++i) {      // zz tile 64x64 = sum of 8 partials
    int slot = tid + i * 256, row = slot >> 4, c4 = (slot & 15) * 4;
    float4 v = float4{0.f, 0.f, 0.f, 0.f};
#pragma unroll
    for (int s = 0; s < 8; ++s) {
      float4 p = *(const float4*)&P2[(s * BB + row) * DD + k0 + c4];
      v.x += p.x; v.y += p.y; v.z += p.z; v.w += p.w;
    }
    *(float4*)&Zs[row][c4] = v;
  }
#pragma unroll
  for (int i = 0; i < 16; ++i) {
    int slot = tid + i * 256, row = slot >> 4, c4 = (slot & 15) * 4;
    *(float4*)&Ws[row][c4] = wreg[i];
  }
  __syncthreads();
  int bg = tid & 7, lg = tid >> 3;   // b = bg+8i, l = l0+lg+32j
  float acc[8][8] = {};
  for (int k = 0; k < 64; k += 4) {
    float4 zv[8], wv[8];
#pragma unroll
    for (int i = 0; i < 8; ++i) zv[i] = *(const float4*)&Zs[bg + 8 * i][k];
#pragma unroll
    for (int j = 0; j < 8; ++j) wv[j] = *(const float4*)&Ws[lg + 32 * j][k];
#pragma unroll
    for (int i = 0; i < 8; ++i)
#pragma unroll
      for (int j = 0; j < 8; ++j)
        acc[i][j] += zv[i].x * wv[j].x + zv[i].y * wv[j].y +
                     zv[i].z * wv[j].z + zv[i].w * wv[j].w;
  }
  // P3 slot (lt*8+ks) so kD (same lt -> same XCD) reads L2-hot
  float* base = P3 + (size_t)(lt * 8 + ks) * 16384 + tid;
#pragma unroll
  for (int i = 0; i < 8; ++i)
#pragma unroll
    for (int j = 0; j < 8; ++j)
      base[(i * 8 + j) * 256] = acc[i][j];
}

// ---------------- kD: reduce 8 k-splits, scale by s[b], coalesced out ---------
// blk: i = blk>>5 (b-octet), lt = blk&31  (XCD blk%8 == lt%8 matches kC writer)
__global__ __launch_bounds__(256) void kD(const float* __restrict__ P3,
                                          const float* __restrict__ sbv,
                                          float* __restrict__ out) {
  __shared__ __align__(16) float T[8][264];
  int tid = threadIdx.x;
  int i = blockIdx.x >> 5, lt = blockIdx.x & 31;
  int bg = tid & 7, lg = tid >> 3;
  float sv = sbv[bg + 8 * i];
#pragma unroll
  for (int j = 0; j < 8; ++j) {
    float v = 0.f;
#pragma unroll
    for (int ks = 0; ks < 8; ++ks)
      v += P3[(size_t)(lt * 8 + ks) * 16384 + (i * 8 + j) * 256 + tid];
    T[bg][lg + 32 * j] = v * sv;
  }
  __syncthreads();
#pragma unroll
  for (int r = 0; r < 2; ++r) {      // 512 float4 slots: 8 rows x 64
    int slot = tid + r * 256;
    int row = slot >> 6, c4 = (slot & 63) * 4;
    float4 v = *(const float4*)&T[row][c4];
    *(float4*)&out[(size_t)(8 * i + row) * LL + lt * 256 + c4] = v;
  }
}

extern "C" void kernel_launch(void* const* d_in, const int* in_sizes, int n_in,
                              void* d_out, int out_size, void* d_ws, size_t ws_size,
                              hipStream_t stream) {
  const float* z      = (const float*)d_in[0];
  const int*   y      = (const int*)  d_in[1];
  const float* W_yemb = (const float*)d_in[2];
  const float* b_yemb = (const float*)d_in[3];
  const float* Wy1    = (const float*)d_in[4];
  const float* by1    = (const float*)d_in[5];
  const float* Wy2    = (const float*)d_in[6];
  const float* by2    = (const float*)d_in[7];
  const float* Wz1    = (const float*)d_in[8];
  const float* bz1    = (const float*)d_in[9];
  const float* Wz2    = (const float*)d_in[10];
  const float* bz2    = (const float*)d_in[11];
  const float* W_zlat = (const float*)d_in[12];
  const float* w_proj = (const float*)d_in[13];

  float* ws = (float*)d_ws;
  float* P1 = ws;                 // [8][64][512]   = 262144
  float* P2 = ws + 262144;        // [8][64][512]   = 262144
  float* P3 = ws + 524288;        // [32*8][16384]  = 4194304
  float* u1 = ws + 4718592;       // [512]
  float* u0 = ws + 4719104;       // [512]
  float* sb = ws + 4719616;       // [64]
  float* d2 = ws + 4719680;       // [1]
  float* out = (float*)d_out;

  kA<<<144, 256, 0, stream>>>(z, Wz1, bz1, P1, Wy2, w_proj, u1);
  kB<<<145, 256, 0, stream>>>(P1, Wz2, bz2, P2, Wy1, u1, u0, by1, by2, w_proj, d2);
  kC<<<264, 256, 0, stream>>>(P2, W_zlat, P3, W_yemb, b_yemb, y, u0, d2, sb);
  kD<<<256, 256, 0, stream>>>(P3, sb, out);
}

// Round 5
// 154.081 us; speedup vs baseline: 1.1617x; 1.0129x over previous
//
#include <hip/hip_runtime.h>

// B=64, D=512 (ZD=E), L=8192, NL=1000, fp32. No atomics. 4 dispatches.
// out[b,l] = s[b] * dot(zz[b,:], W_zlat[l,:])
//   zz = irm(z, Wz1/bz1, Wz2/bz2)  via split-K-8 partials, re-summed during staging
//   e-path collapsed: u1 = w_proj + Wy2^T w_proj; u0 = u1 + Wy1^T u1
//   s[b] = sum_e (W_yemb[e,y[b]]+b_yemb[e])*u0[e] + by1.u1 + by2.w_proj
// kC uses 80 KB LDS (pitch 64, XOR bank swizzle) -> 2 blocks/CU so staging of
// one block overlaps compute of the co-resident one.

#define BB 64
#define DD 512
#define LL 8192
#define NLBL 1000
#define PIT 68   // (kA/kB only) LDS pitch: rows 4 banks apart

// ---------- matvec: vout = vin + W^T vin (one 32-wide e-chunk) ----------
__device__ __forceinline__ void matvec_block(int eblk, const float* __restrict__ W,
                                             const float* __restrict__ vin,
                                             float* __restrict__ vout) {
  __shared__ float vl[DD];
  __shared__ float red[256];
  int tid = threadIdx.x;
  vl[tid] = vin[tid];
  vl[tid + 256] = vin[tid + 256];
  __syncthreads();
  int el = tid & 31, jg = tid >> 5;
  int e = eblk * 32 + el;
  float acc = 0.f;
  for (int j = jg; j < DD; j += 8)
    acc += W[j * DD + e] * vl[j];
  red[tid] = acc;
  __syncthreads();
  if (tid < 32) {
    float s = vl[eblk * 32 + tid];
#pragma unroll
    for (int g = 0; g < 8; ++g) s += red[g * 32 + tid];
    vout[eblk * 32 + tid] = s;
  }
}

// ---------- layer GEMM, split-K 8, plain partial stores ----------
// P[ks][b][j]; ks==0 partial carries residual X[b,j] + bias[j].
template <int FIRST>
__device__ __forceinline__ void layer_gemm(int blk, const float* __restrict__ Xg,
                                           const float* __restrict__ P1,
                                           const float* __restrict__ W,
                                           const float* __restrict__ bias,
                                           float* __restrict__ P) {
  __shared__ __align__(16) float Xs[BB][PIT];
  __shared__ __align__(16) float Ws[32][PIT];
  int tid = threadIdx.x;
  int jt = blk >> 3, ks = blk & 7;
  int j0 = jt * 32, k0 = ks * 64;
#pragma unroll
  for (int i = 0; i < 4; ++i) {      // X tile 64x64
    int slot = tid + i * 256, row = slot >> 4, c4 = (slot & 15) * 4;
    float4 v;
    if (FIRST) {
      v = *(const float4*)&Xg[row * DD + k0 + c4];
    } else {
      v = float4{0.f, 0.f, 0.f, 0.f};
#pragma unroll
      for (int s = 0; s < 8; ++s) {
        float4 p = *(const float4*)&P1[(s * BB + row) * DD + k0 + c4];
        v.x += p.x; v.y += p.y; v.z += p.z; v.w += p.w;
      }
    }
    *(float4*)&Xs[row][c4] = v;
  }
#pragma unroll
  for (int i = 0; i < 2; ++i) {      // W tile 32x64
    int slot = tid + i * 256, row = slot >> 4, c4 = (slot & 15) * 4;
    *(float4*)&Ws[row][c4] = *(const float4*)&W[(j0 + row) * DD + k0 + c4];
  }
  __syncthreads();
  int jl = tid & 15, bl = tid >> 4;  // j = j0+jl+16u, b = bl+16i
  float acc[4][2] = {};
#pragma unroll
  for (int k = 0; k < 64; k += 4) {
    float4 xv[4], wv[2];
#pragma unroll
    for (int i = 0; i < 4; ++i) xv[i] = *(const float4*)&Xs[bl + 16 * i][k];
#pragma unroll
    for (int u = 0; u < 2; ++u) wv[u] = *(const float4*)&Ws[jl + 16 * u][k];
#pragma unroll
    for (int i = 0; i < 4; ++i)
#pragma unroll
      for (int u = 0; u < 2; ++u)
        acc[i][u] += xv[i].x * wv[u].x + xv[i].y * wv[u].y +
                     xv[i].z * wv[u].z + xv[i].w * wv[u].w;
  }
#pragma unroll
  for (int i = 0; i < 4; ++i) {
    int b = bl + 16 * i;
#pragma unroll
    for (int u = 0; u < 2; ++u) {
      int jj = j0 + jl + 16 * u;
      float v = acc[i][u];
      if (ks == 0) {
        float xr;
        if (FIRST) {
          xr = Xg[b * DD + jj];
        } else {
          xr = 0.f;
#pragma unroll
          for (int s = 0; s < 8; ++s) xr += P1[(s * BB + b) * DD + jj];
        }
        v += xr + bias[jj];
      }
      P[(ks * BB + b) * DD + jj] = v;
    }
  }
}

// ---------------- kA: layer1 partials + u1 matvec ----------------
__global__ __launch_bounds__(256) void kA(const float* __restrict__ z,
                                          const float* __restrict__ Wz1,
                                          const float* __restrict__ bz1,
                                          float* __restrict__ P1,
                                          const float* __restrict__ Wy2,
                                          const float* __restrict__ w_proj,
                                          float* __restrict__ u1) {
  int blk = blockIdx.x;
  if (blk < 128) layer_gemm<1>(blk, z, nullptr, Wz1, bz1, P1);
  else           matvec_block(blk - 128, Wy2, w_proj, u1);
}

// ---------------- kB: layer2 partials + u0 matvec + d2 scalar ----------------
__global__ __launch_bounds__(256) void kB(const float* __restrict__ P1,
                                          const float* __restrict__ Wz2,
                                          const float* __restrict__ bz2,
                                          float* __restrict__ P2,
                                          const float* __restrict__ Wy1,
                                          const float* __restrict__ u1,
                                          float* __restrict__ u0,
                                          const float* __restrict__ by1,
                                          const float* __restrict__ by2,
                                          const float* __restrict__ w_proj,
                                          float* __restrict__ d2) {
  int blk = blockIdx.x;
  if (blk < 128) {
    layer_gemm<0>(blk, nullptr, P1, Wz2, bz2, P2);
  } else if (blk < 144) {
    matvec_block(blk - 128, Wy1, u1, u0);
  } else {
    __shared__ float red[256];
    int tid = threadIdx.x;
    float p = by1[tid] * u1[tid] + by2[tid] * w_proj[tid] +
              by1[tid + 256] * u1[tid + 256] + by2[tid + 256] * w_proj[tid + 256];
    red[tid] = p;
    __syncthreads();
    if (tid < 64) {
      float s = red[tid] + red[tid + 64] + red[tid + 128] + red[tid + 192];
#pragma unroll
      for (int d = 32; d; d >>= 1) s += __shfl_down(s, d, 64);
      if (tid == 0) d2[0] = s;
    }
  }
}

// ---------------- kC: GEMM partials (split-K 8, 8b x 8l) + s[b] gather-dot ----
// GEMM blocks 0..255: ks = blk>>5, lt = blk&31 (XCD blk%8 == lt%8, matches kD).
// 80 KB LDS: pitch 64, XOR swizzle phys_c4 = c4 ^ (row&7)  -> 2 blocks/CU,
// conflict-free reads (row&7 permutes the 8 4-bank groups within each wave).
__global__ __launch_bounds__(256) void kC(const float* __restrict__ P2,
                                          const float* __restrict__ W,
                                          float* __restrict__ P3,
                                          const float* __restrict__ W_yemb,
                                          const float* __restrict__ b_yemb,
                                          const int* __restrict__ y,
                                          const float* __restrict__ u0,
                                          const float* __restrict__ d2,
                                          float* __restrict__ sbv) {
  __shared__ __align__(16) float S[16384 + 4096];   // Ws'[256][64] + Zs'[64][64]
  float* Wsl = S;
  float* Zsl = S + 16384;
  int blk = blockIdx.x;
  int tid = threadIdx.x;
  if (blk >= 256) {                  // ---- s-gather: 8 blocks x 8 batches ----
    float* u0l = S;                  // alias, no extra LDS
    u0l[tid] = u0[tid];
    u0l[tid + 256] = u0[tid + 256];
    __syncthreads();
    int bl = tid >> 5, el = tid & 31;
    int b = (blk - 256) * 8 + bl;
    int yb = y[b];
    float acc = 0.f;
    for (int e = el; e < DD; e += 32)
      acc += (W_yemb[(size_t)e * NLBL + yb] + b_yemb[e]) * u0l[e];
#pragma unroll
    for (int d = 16; d; d >>= 1) acc += __shfl_down(acc, d, 32);
    if (el == 0) sbv[b] = acc + d2[0];
    return;
  }
  int ks = blk >> 5, lt = blk & 31;
  int l0 = lt * 256, k0 = ks * 64;
  // issue W global loads first (registers), overlap latency with P2-sum staging
  float4 wreg[16];
#pragma unroll
  for (int i = 0; i < 16; ++i) {
    int slot = tid + i * 256, row = slot >> 4, c4 = (slot & 15) * 4;
    wreg[i] = *(const float4*)&W[(size_t)(l0 + row) * DD + k0 + c4];
  }
#pragma unroll
  for (int i = 0; i < 4; ++i) {      // zz tile 64x64 = sum of 8 partials
    int slot = tid + i * 256, row = slot >> 4, c4 = slot & 15;
    float4 v = float4{0.f, 0.f, 0.f, 0.f};
#pragma unroll
    for (int s = 0; s < 8; ++s) {
      float4 p = *(const float4*)&P2[(s * BB + row) * DD + k0 + c4 * 4];
      v.x += p.x; v.y += p.y; v.z += p.z; v.w += p.w;
    }
    *(float4*)&Zsl[row * 64 + ((c4 ^ (row & 7)) << 2)] = v;
  }
#pragma unroll
  for (int i = 0; i < 16; ++i) {
    int slot = tid + i * 256, row = slot >> 4, c4 = slot & 15;
    *(float4*)&Wsl[row * 64 + ((c4 ^ (row & 7)) << 2)] = wreg[i];
  }
  __syncthreads();
  int bg = tid & 7, lg = tid >> 3;   // b = bg+8i, l = l0+lg+32j
  int lg7 = lg & 7;
  float acc[8][8] = {};
#pragma unroll
  for (int k4 = 0; k4 < 16; ++k4) {
    int offz = ((k4 ^ bg) << 2);     // same for all 8 zv rows (row&7 == bg)
    int offw = ((k4 ^ lg7) << 2);    // same for all 8 wv rows (row&7 == lg&7)
    float4 zv[8], wv[8];
#pragma unroll
    for (int i = 0; i < 8; ++i) zv[i] = *(const float4*)&Zsl[(bg + 8 * i) * 64 + offz];
#pragma unroll
    for (int j = 0; j < 8; ++j) wv[j] = *(const float4*)&Wsl[(lg + 32 * j) * 64 + offw];
#pragma unroll
    for (int i = 0; i < 8; ++i)
#pragma unroll
      for (int j = 0; j < 8; ++j)
        acc[i][j] += zv[i].x * wv[j].x + zv[i].y * wv[j].y +
                     zv[i].z * wv[j].z + zv[i].w * wv[j].w;
  }
  // P3 slot (lt*8+ks) so kD (same lt -> same XCD) reads L2-hot
  float* base = P3 + (size_t)(lt * 8 + ks) * 16384 + tid;
#pragma unroll
  for (int i = 0; i < 8; ++i)
#pragma unroll
    for (int j = 0; j < 8; ++j)
      base[(i * 8 + j) * 256] = acc[i][j];
}

// ---------------- kD: reduce 8 k-splits, scale by s[b], coalesced out ---------
// blk: i = blk>>5 (b-octet), lt = blk&31  (XCD blk%8 == lt%8 matches kC writer)
__global__ __launch_bounds__(256) void kD(const float* __restrict__ P3,
                                          const float* __restrict__ sbv,
                                          float* __restrict__ out) {
  __shared__ __align__(16) float T[8][264];
  int tid = threadIdx.x;
  int i = blockIdx.x >> 5, lt = blockIdx.x & 31;
  int bg = tid & 7, lg = tid >> 3;
  float sv = sbv[bg + 8 * i];
#pragma unroll
  for (int j = 0; j < 8; ++j) {
    float v = 0.f;
#pragma unroll
    for (int ks = 0; ks < 8; ++ks)
      v += P3[(size_t)(lt * 8 + ks) * 16384 + (i * 8 + j) * 256 + tid];
    T[bg][lg + 32 * j] = v * sv;
  }
  __syncthreads();
#pragma unroll
  for (int r = 0; r < 2; ++r) {      // 512 float4 slots: 8 rows x 64
    int slot = tid + r * 256;
    int row = slot >> 6, c4 = (slot & 63) * 4;
    float4 v = *(const float4*)&T[row][c4];
    *(float4*)&out[(size_t)(8 * i + row) * LL + lt * 256 + c4] = v;
  }
}

extern "C" void kernel_launch(void* const* d_in, const int* in_sizes, int n_in,
                              void* d_out, int out_size, void* d_ws, size_t ws_size,
                              hipStream_t stream) {
  const float* z      = (const float*)d_in[0];
  const int*   y      = (const int*)  d_in[1];
  const float* W_yemb = (const float*)d_in[2];
  const float* b_yemb = (const float*)d_in[3];
  const float* Wy1    = (const float*)d_in[4];
  const float* by1    = (const float*)d_in[5];
  const float* Wy2    = (const float*)d_in[6];
  const float* by2    = (const float*)d_in[7];
  const float* Wz1    = (const float*)d_in[8];
  const float* bz1    = (const float*)d_in[9];
  const float* Wz2    = (const float*)d_in[10];
  const float* bz2    = (const float*)d_in[11];
  const float* W_zlat = (const float*)d_in[12];
  const float* w_proj = (const float*)d_in[13];

  float* ws = (float*)d_ws;
  float* P1 = ws;                 // [8][64][512]   = 262144
  float* P2 = ws + 262144;        // [8][64][512]   = 262144
  float* P3 = ws + 524288;        // [32*8][16384]  = 4194304
  float* u1 = ws + 4718592;       // [512]
  float* u0 = ws + 4719104;       // [512]
  float* sb = ws + 4719616;       // [64]
  float* d2 = ws + 4719680;       // [1]
  float* out = (float*)d_out;

  kA<<<144, 256, 0, stream>>>(z, Wz1, bz1, P1, Wy2, w_proj, u1);
  kB<<<145, 256, 0, stream>>>(P1, Wz2, bz2, P2, Wy1, u1, u0, by1, by2, w_proj, d2);
  kC<<<264, 256, 0, stream>>>(P2, W_zlat, P3, W_yemb, b_yemb, y, u0, d2, sb);
  kD<<<256, 256, 0, stream>>>(P3, sb, out);
}

// Round 6
// 153.811 us; speedup vs baseline: 1.1638x; 1.0018x over previous
//
#include <hip/hip_runtime.h>

// B=64, D=512 (ZD=E), L=8192, NL=1000, fp32 in/out. No atomics. 4 dispatches.
// out[b,l] = s[b] * dot(zz[b,:], W_zlat[l,:])
//   zz = irm(z, Wz1/bz1, Wz2/bz2)  via split-K-8 partials (fp32)
//   e-path collapsed: u1 = w_proj + Wy2^T w_proj; u0 = u1 + Wy1^T u1
//   s[b] = sum_e (W_yemb[e,y[b]]+b_yemb[e])*u0[e] + by1.u1 + by2.w_proj
// kC: big GEMM in bf16 MFMA (16x16x32), inputs quantized on the fly.
//     LDS 40 KB: A 64x64 bf16 + B 256x64 bf16, XOR-16B-group bank swizzle.
// kD: plain [slot][b][l] reduce, XCD-local to kC via lt = blk&31 on both.

#define BB 64
#define DD 512
#define LL 8192
#define NLBL 1000
#define PIT 68   // (kA/kB only) LDS pitch

typedef __attribute__((ext_vector_type(8))) short short8;
typedef __attribute__((ext_vector_type(4))) float f32x4;

__device__ __forceinline__ unsigned short f2bf(float f) {
  unsigned u = __float_as_uint(f);
  return (unsigned short)((u + 0x7fffu + ((u >> 16) & 1u)) >> 16);   // RNE
}

// ---------- matvec: vout = vin + W^T vin (one 32-wide e-chunk) ----------
__device__ __forceinline__ void matvec_block(int eblk, const float* __restrict__ W,
                                             const float* __restrict__ vin,
                                             float* __restrict__ vout) {
  __shared__ float vl[DD];
  __shared__ float red[256];
  int tid = threadIdx.x;
  vl[tid] = vin[tid];
  vl[tid + 256] = vin[tid + 256];
  __syncthreads();
  int el = tid & 31, jg = tid >> 5;
  int e = eblk * 32 + el;
  float acc = 0.f;
  for (int j = jg; j < DD; j += 8)
    acc += W[j * DD + e] * vl[j];
  red[tid] = acc;
  __syncthreads();
  if (tid < 32) {
    float s = vl[eblk * 32 + tid];
#pragma unroll
    for (int g = 0; g < 8; ++g) s += red[g * 32 + tid];
    vout[eblk * 32 + tid] = s;
  }
}

// ---------- layer GEMM, split-K 8, plain partial stores (fp32) ----------
template <int FIRST>
__device__ __forceinline__ void layer_gemm(int blk, const float* __restrict__ Xg,
                                           const float* __restrict__ P1,
                                           const float* __restrict__ W,
                                           const float* __restrict__ bias,
                                           float* __restrict__ P) {
  __shared__ __align__(16) float Xs[BB][PIT];
  __shared__ __align__(16) float Ws[32][PIT];
  int tid = threadIdx.x;
  int jt = blk >> 3, ks = blk & 7;
  int j0 = jt * 32, k0 = ks * 64;
#pragma unroll
  for (int i = 0; i < 4; ++i) {      // X tile 64x64
    int slot = tid + i * 256, row = slot >> 4, c4 = (slot & 15) * 4;
    float4 v;
    if (FIRST) {
      v = *(const float4*)&Xg[row * DD + k0 + c4];
    } else {
      v = float4{0.f, 0.f, 0.f, 0.f};
#pragma unroll
      for (int s = 0; s < 8; ++s) {
        float4 p = *(const float4*)&P1[(s * BB + row) * DD + k0 + c4];
        v.x += p.x; v.y += p.y; v.z += p.z; v.w += p.w;
      }
    }
    *(float4*)&Xs[row][c4] = v;
  }
#pragma unroll
  for (int i = 0; i < 2; ++i) {      // W tile 32x64
    int slot = tid + i * 256, row = slot >> 4, c4 = (slot & 15) * 4;
    *(float4*)&Ws[row][c4] = *(const float4*)&W[(j0 + row) * DD + k0 + c4];
  }
  __syncthreads();
  int jl = tid & 15, bl = tid >> 4;
  float acc[4][2] = {};
#pragma unroll
  for (int k = 0; k < 64; k += 4) {
    float4 xv[4], wv[2];
#pragma unroll
    for (int i = 0; i < 4; ++i) xv[i] = *(const float4*)&Xs[bl + 16 * i][k];
#pragma unroll
    for (int u = 0; u < 2; ++u) wv[u] = *(const float4*)&Ws[jl + 16 * u][k];
#pragma unroll
    for (int i = 0; i < 4; ++i)
#pragma unroll
      for (int u = 0; u < 2; ++u)
        acc[i][u] += xv[i].x * wv[u].x + xv[i].y * wv[u].y +
                     xv[i].z * wv[u].z + xv[i].w * wv[u].w;
  }
#pragma unroll
  for (int i = 0; i < 4; ++i) {
    int b = bl + 16 * i;
#pragma unroll
    for (int u = 0; u < 2; ++u) {
      int jj = j0 + jl + 16 * u;
      float v = acc[i][u];
      if (ks == 0) {
        float xr;
        if (FIRST) {
          xr = Xg[b * DD + jj];
        } else {
          xr = 0.f;
#pragma unroll
          for (int s = 0; s < 8; ++s) xr += P1[(s * BB + b) * DD + jj];
        }
        v += xr + bias[jj];
      }
      P[(ks * BB + b) * DD + jj] = v;
    }
  }
}

// ---------------- kA: layer1 partials + u1 matvec ----------------
__global__ __launch_bounds__(256) void kA(const float* __restrict__ z,
                                          const float* __restrict__ Wz1,
                                          const float* __restrict__ bz1,
                                          float* __restrict__ P1,
                                          const float* __restrict__ Wy2,
                                          const float* __restrict__ w_proj,
                                          float* __restrict__ u1) {
  int blk = blockIdx.x;
  if (blk < 128) layer_gemm<1>(blk, z, nullptr, Wz1, bz1, P1);
  else           matvec_block(blk - 128, Wy2, w_proj, u1);
}

// ---------------- kB: layer2 partials + u0 matvec + d2 scalar ----------------
__global__ __launch_bounds__(256) void kB(const float* __restrict__ P1,
                                          const float* __restrict__ Wz2,
                                          const float* __restrict__ bz2,
                                          float* __restrict__ P2,
                                          const float* __restrict__ Wy1,
                                          const float* __restrict__ u1,
                                          float* __restrict__ u0,
                                          const float* __restrict__ by1,
                                          const float* __restrict__ by2,
                                          const float* __restrict__ w_proj,
                                          float* __restrict__ d2) {
  int blk = blockIdx.x;
  if (blk < 128) {
    layer_gemm<0>(blk, nullptr, P1, Wz2, bz2, P2);
  } else if (blk < 144) {
    matvec_block(blk - 128, Wy1, u1, u0);
  } else {
    __shared__ float red[256];
    int tid = threadIdx.x;
    float p = by1[tid] * u1[tid] + by2[tid] * w_proj[tid] +
              by1[tid + 256] * u1[tid + 256] + by2[tid + 256] * w_proj[tid + 256];
    red[tid] = p;
    __syncthreads();
    if (tid < 64) {
      float s = red[tid] + red[tid + 64] + red[tid + 128] + red[tid + 192];
#pragma unroll
      for (int d = 32; d; d >>= 1) s += __shfl_down(s, d, 64);
      if (tid == 0) d2[0] = s;
    }
  }
}

// ---------------- kC: bf16-MFMA GEMM partials + s[b] gather-dot --------------
// GEMM blocks 0..255: ks = blk>>5 (k-chunk 64), lt = blk&31 (l-tile 256).
// LDS: Bs 256x64 bf16 (32 KB) + As 64x64 bf16 (8 KB) = 40 KB.
// Row = 64 bf16 = 128 B = 8 groups of 16 B; phys group = g ^ (row&7).
// P3 layout: [(lt*8+ks)][b 64][l 256] fp32.
__global__ __launch_bounds__(256) void kC(const float* __restrict__ P2,
                                          const float* __restrict__ W,
                                          float* __restrict__ P3,
                                          const float* __restrict__ W_yemb,
                                          const float* __restrict__ b_yemb,
                                          const int* __restrict__ y,
                                          const float* __restrict__ u0,
                                          const float* __restrict__ d2,
                                          float* __restrict__ sbv) {
  __shared__ __align__(16) unsigned short LB[(256 + 64) * 64];  // Bs | As
  unsigned short* Bs = LB;
  unsigned short* As = LB + 256 * 64;
  int blk = blockIdx.x;
  int tid = threadIdx.x;
  if (blk >= 256) {                  // ---- s-gather: 8 blocks x 8 batches ----
    float* u0l = (float*)LB;
    u0l[tid] = u0[tid];
    u0l[tid + 256] = u0[tid + 256];
    __syncthreads();
    int bl = tid >> 5, el = tid & 31;
    int b = (blk - 256) * 8 + bl;
    int yb = y[b];
    float acc = 0.f;
    for (int e = el; e < DD; e += 32)
      acc += (W_yemb[(size_t)e * NLBL + yb] + b_yemb[e]) * u0l[e];
#pragma unroll
    for (int d = 16; d; d >>= 1) acc += __shfl_down(acc, d, 32);
    if (el == 0) sbv[b] = acc + d2[0];
    return;
  }
  int ks = blk >> 5, lt = blk & 31;
  int l0 = lt * 256, k0 = ks * 64;
  // --- stage W (fp32 HBM -> bf16 LDS), 16 float4/thread, swizzled b64 writes
#pragma unroll
  for (int i = 0; i < 16; ++i) {
    int slot = tid + i * 256, row = slot >> 4, c4 = slot & 15;
    float4 v = *(const float4*)&W[(size_t)(l0 + row) * DD + k0 + c4 * 4];
    ushort4 h = {f2bf(v.x), f2bf(v.y), f2bf(v.z), f2bf(v.w)};
    int g = c4 >> 1, half = c4 & 1;
    *(ushort4*)&Bs[row * 64 + (((g ^ (row & 7)) << 3) + half * 4)] = h;
  }
  // --- stage A = zz = sum of 8 P2 partials (fp32 -> bf16)
#pragma unroll
  for (int i = 0; i < 4; ++i) {
    int slot = tid + i * 256, row = slot >> 4, c4 = slot & 15;
    float4 v = float4{0.f, 0.f, 0.f, 0.f};
#pragma unroll
    for (int s = 0; s < 8; ++s) {
      float4 p = *(const float4*)&P2[(s * BB + row) * DD + k0 + c4 * 4];
      v.x += p.x; v.y += p.y; v.z += p.z; v.w += p.w;
    }
    ushort4 h = {f2bf(v.x), f2bf(v.y), f2bf(v.z), f2bf(v.w)};
    int g = c4 >> 1, half = c4 & 1;
    *(ushort4*)&As[row * 64 + (((g ^ (row & 7)) << 3) + half * 4)] = h;
  }
  __syncthreads();
  // --- MFMA: wave w covers l-range [w*64, w*64+64), all 64 b.
  int wave = tid >> 6, lane = tid & 63;
  int quad = lane >> 4, l15 = lane & 15;
  f32x4 acc[4][4] = {};                    // [mi][ni]
#pragma unroll
  for (int kstep = 0; kstep < 2; ++kstep) {
    int g = kstep * 4 + quad;              // k-group for this lane
    short8 af[4], bf[4];
#pragma unroll
    for (int mi = 0; mi < 4; ++mi) {
      int m = mi * 16 + l15;
      af[mi] = *(const short8*)&As[m * 64 + ((g ^ (m & 7)) << 3)];
    }
#pragma unroll
    for (int ni = 0; ni < 4; ++ni) {
      int n = wave * 64 + ni * 16 + l15;
      bf[ni] = *(const short8*)&Bs[n * 64 + ((g ^ (n & 7)) << 3)];
    }
#pragma unroll
    for (int mi = 0; mi < 4; ++mi)
#pragma unroll
      for (int ni = 0; ni < 4; ++ni)
        acc[mi][ni] = __builtin_amdgcn_mfma_f32_16x16x32_bf16(
            af[mi], bf[ni], acc[mi][ni], 0, 0, 0);
  }
  // --- store P3[(lt*8+ks)][b][l]:  b = mi*16+quad*4+reg, l = wave*64+ni*16+l15
  float* base = P3 + (size_t)(lt * 8 + ks) * 16384;
#pragma unroll
  for (int mi = 0; mi < 4; ++mi)
#pragma unroll
    for (int ni = 0; ni < 4; ++ni) {
      int l = wave * 64 + ni * 16 + l15;
#pragma unroll
      for (int reg = 0; reg < 4; ++reg) {
        int b = mi * 16 + quad * 4 + reg;
        base[b * 256 + l] = acc[mi][ni][reg];
      }
    }
}

// ---------------- kD: reduce 8 k-splits, scale by s[b], coalesced out ---------
// blk: i = blk>>5 (b-octet), lt = blk&31 (XCD match with kC writer).
__global__ __launch_bounds__(256) void kD(const float* __restrict__ P3,
                                          const float* __restrict__ sbv,
                                          float* __restrict__ out) {
  int t = threadIdx.x;
  int i = blockIdx.x >> 5, lt = blockIdx.x & 31;
  int b = i * 8 + (t >> 5);
  int c = (t & 31) * 8;
  const float* base = P3 + (size_t)(lt * 8) * 16384 + b * 256 + c;
  float4 a0 = {0.f, 0.f, 0.f, 0.f}, a1 = {0.f, 0.f, 0.f, 0.f};
#pragma unroll
  for (int ks = 0; ks < 8; ++ks) {
    float4 p = *(const float4*)(base + (size_t)ks * 16384);
    float4 q = *(const float4*)(base + (size_t)ks * 16384 + 4);
    a0.x += p.x; a0.y += p.y; a0.z += p.z; a0.w += p.w;
    a1.x += q.x; a1.y += q.y; a1.z += q.z; a1.w += q.w;
  }
  float sv = sbv[b];
  a0.x *= sv; a0.y *= sv; a0.z *= sv; a0.w *= sv;
  a1.x *= sv; a1.y *= sv; a1.z *= sv; a1.w *= sv;
  float* o = out + (size_t)b * LL + lt * 256 + c;
  *(float4*)o = a0;
  *(float4*)(o + 4) = a1;
}

extern "C" void kernel_launch(void* const* d_in, const int* in_sizes, int n_in,
                              void* d_out, int out_size, void* d_ws, size_t ws_size,
                              hipStream_t stream) {
  const float* z      = (const float*)d_in[0];
  const int*   y      = (const int*)  d_in[1];
  const float* W_yemb = (const float*)d_in[2];
  const float* b_yemb = (const float*)d_in[3];
  const float* Wy1    = (const float*)d_in[4];
  const float* by1    = (const float*)d_in[5];
  const float* Wy2    = (const float*)d_in[6];
  const float* by2    = (const float*)d_in[7];
  const float* Wz1    = (const float*)d_in[8];
  const float* bz1    = (const float*)d_in[9];
  const float* Wz2    = (const float*)d_in[10];
  const float* bz2    = (const float*)d_in[11];
  const float* W_zlat = (const float*)d_in[12];
  const float* w_proj = (const float*)d_in[13];

  float* ws = (float*)d_ws;
  float* P1 = ws;                 // [8][64][512]   = 262144
  float* P2 = ws + 262144;        // [8][64][512]   = 262144
  float* P3 = ws + 524288;        // [32*8][64][256]= 4194304
  float* u1 = ws + 4718592;       // [512]
  float* u0 = ws + 4719104;       // [512]
  float* sb = ws + 4719616;       // [64]
  float* d2 = ws + 4719680;       // [1]
  float* out = (float*)d_out;

  kA<<<144, 256, 0, stream>>>(z, Wz1, bz1, P1, Wy2, w_proj, u1);
  kB<<<145, 256, 0, stream>>>(P1, Wz2, bz2, P2, Wy1, u1, u0, by1, by2, w_proj, d2);
  kC<<<264, 256, 0, stream>>>(P2, W_zlat, P3, W_yemb, b_yemb, y, u0, d2, sb);
  kD<<<256, 256, 0, stream>>>(P3, sb, out);
}

// Round 7
// 143.630 us; speedup vs baseline: 1.2462x; 1.0709x over previous
//
#include <hip/hip_runtime.h>

// B=64, D=512 (ZD=E), L=8192, NL=1000, fp32 in/out. No atomics. 4 dispatches.
// out[b,l] = s[b] * dot(zz[b,:], W_zlat[l,:])
//   zz = irm(z, Wz1/bz1, Wz2/bz2): layer1 split-K-8 -> P1 (kA), layer2 split-K-8
//        -> P2 (kB), P2 reduced to bf16 zz in kZ.
//   e-path collapsed: u1 = w_proj + Wy2^T w_proj (kA); u0 = u1 + Wy1^T u1 (kB);
//   s[b] = sum_e (W_yemb[e,y[b]]+b_yemb[e])*u0[e] + by1.u1 + by2.w_proj (kZ).
// kC: direct bf16-MFMA GEMM, full K=512 per block, 32-l-tile, scaled store to out.
//     No P3 materialization, kD eliminated.

#define BB 64
#define DD 512
#define LL 8192
#define NLBL 1000
#define PIT 68   // (kA/kB only) LDS pitch

typedef __attribute__((ext_vector_type(8))) short short8;
typedef __attribute__((ext_vector_type(4))) float f32x4;

__device__ __forceinline__ unsigned short f2bf(float f) {
  unsigned u = __float_as_uint(f);
  return (unsigned short)((u + 0x7fffu + ((u >> 16) & 1u)) >> 16);   // RNE
}

// ---------- matvec: vout = vin + W^T vin (one 32-wide e-chunk) ----------
__device__ __forceinline__ void matvec_block(int eblk, const float* __restrict__ W,
                                             const float* __restrict__ vin,
                                             float* __restrict__ vout) {
  __shared__ float vl[DD];
  __shared__ float red[256];
  int tid = threadIdx.x;
  vl[tid] = vin[tid];
  vl[tid + 256] = vin[tid + 256];
  __syncthreads();
  int el = tid & 31, jg = tid >> 5;
  int e = eblk * 32 + el;
  float acc = 0.f;
  for (int j = jg; j < DD; j += 8)
    acc += W[j * DD + e] * vl[j];
  red[tid] = acc;
  __syncthreads();
  if (tid < 32) {
    float s = vl[eblk * 32 + tid];
#pragma unroll
    for (int g = 0; g < 8; ++g) s += red[g * 32 + tid];
    vout[eblk * 32 + tid] = s;
  }
}

// ---------- layer GEMM, split-K 8, plain partial stores (fp32) ----------
template <int FIRST>
__device__ __forceinline__ void layer_gemm(int blk, const float* __restrict__ Xg,
                                           const float* __restrict__ P1,
                                           const float* __restrict__ W,
                                           const float* __restrict__ bias,
                                           float* __restrict__ P) {
  __shared__ __align__(16) float Xs[BB][PIT];
  __shared__ __align__(16) float Ws[32][PIT];
  int tid = threadIdx.x;
  int jt = blk >> 3, ks = blk & 7;
  int j0 = jt * 32, k0 = ks * 64;
#pragma unroll
  for (int i = 0; i < 4; ++i) {      // X tile 64x64
    int slot = tid + i * 256, row = slot >> 4, c4 = (slot & 15) * 4;
    float4 v;
    if (FIRST) {
      v = *(const float4*)&Xg[row * DD + k0 + c4];
    } else {
      v = float4{0.f, 0.f, 0.f, 0.f};
#pragma unroll
      for (int s = 0; s < 8; ++s) {
        float4 p = *(const float4*)&P1[(s * BB + row) * DD + k0 + c4];
        v.x += p.x; v.y += p.y; v.z += p.z; v.w += p.w;
      }
    }
    *(float4*)&Xs[row][c4] = v;
  }
#pragma unroll
  for (int i = 0; i < 2; ++i) {      // W tile 32x64
    int slot = tid + i * 256, row = slot >> 4, c4 = (slot & 15) * 4;
    *(float4*)&Ws[row][c4] = *(const float4*)&W[(j0 + row) * DD + k0 + c4];
  }
  __syncthreads();
  int jl = tid & 15, bl = tid >> 4;
  float acc[4][2] = {};
#pragma unroll
  for (int k = 0; k < 64; k += 4) {
    float4 xv[4], wv[2];
#pragma unroll
    for (int i = 0; i < 4; ++i) xv[i] = *(const float4*)&Xs[bl + 16 * i][k];
#pragma unroll
    for (int u = 0; u < 2; ++u) wv[u] = *(const float4*)&Ws[jl + 16 * u][k];
#pragma unroll
    for (int i = 0; i < 4; ++i)
#pragma unroll
      for (int u = 0; u < 2; ++u)
        acc[i][u] += xv[i].x * wv[u].x + xv[i].y * wv[u].y +
                     xv[i].z * wv[u].z + xv[i].w * wv[u].w;
  }
#pragma unroll
  for (int i = 0; i < 4; ++i) {
    int b = bl + 16 * i;
#pragma unroll
    for (int u = 0; u < 2; ++u) {
      int jj = j0 + jl + 16 * u;
      float v = acc[i][u];
      if (ks == 0) {
        float xr;
        if (FIRST) {
          xr = Xg[b * DD + jj];
        } else {
          xr = 0.f;
#pragma unroll
          for (int s = 0; s < 8; ++s) xr += P1[(s * BB + b) * DD + jj];
        }
        v += xr + bias[jj];
      }
      P[(ks * BB + b) * DD + jj] = v;
    }
  }
}

// ---------------- kA: layer1 partials + u1 matvec ----------------
__global__ __launch_bounds__(256) void kA(const float* __restrict__ z,
                                          const float* __restrict__ Wz1,
                                          const float* __restrict__ bz1,
                                          float* __restrict__ P1,
                                          const float* __restrict__ Wy2,
                                          const float* __restrict__ w_proj,
                                          float* __restrict__ u1) {
  int blk = blockIdx.x;
  if (blk < 128) layer_gemm<1>(blk, z, nullptr, Wz1, bz1, P1);
  else           matvec_block(blk - 128, Wy2, w_proj, u1);
}

// ---------------- kB: layer2 partials + u0 matvec + d2 scalar ----------------
__global__ __launch_bounds__(256) void kB(const float* __restrict__ P1,
                                          const float* __restrict__ Wz2,
                                          const float* __restrict__ bz2,
                                          float* __restrict__ P2,
                                          const float* __restrict__ Wy1,
                                          const float* __restrict__ u1,
                                          float* __restrict__ u0,
                                          const float* __restrict__ by1,
                                          const float* __restrict__ by2,
                                          const float* __restrict__ w_proj,
                                          float* __restrict__ d2) {
  int blk = blockIdx.x;
  if (blk < 128) {
    layer_gemm<0>(blk, nullptr, P1, Wz2, bz2, P2);
  } else if (blk < 144) {
    matvec_block(blk - 128, Wy1, u1, u0);
  } else {
    __shared__ float red[256];
    int tid = threadIdx.x;
    float p = by1[tid] * u1[tid] + by2[tid] * w_proj[tid] +
              by1[tid + 256] * u1[tid + 256] + by2[tid + 256] * w_proj[tid + 256];
    red[tid] = p;
    __syncthreads();
    if (tid < 64) {
      float s = red[tid] + red[tid + 64] + red[tid + 128] + red[tid + 192];
#pragma unroll
      for (int d = 32; d; d >>= 1) s += __shfl_down(s, d, 64);
      if (tid == 0) d2[0] = s;
    }
  }
}

// ---------------- kZ: reduce P2 -> zz(bf16) + s[b] gather-dot ----------------
// blocks 0..15: zzbf[b,k] = bf16( sum_s P2[s][b][k] ), 2048 elems/block.
// blocks 16..23: s-gather (8 batches each).
__global__ __launch_bounds__(256) void kZ(const float* __restrict__ P2,
                                          unsigned short* __restrict__ zzbf,
                                          const float* __restrict__ W_yemb,
                                          const float* __restrict__ b_yemb,
                                          const int* __restrict__ y,
                                          const float* __restrict__ u0,
                                          const float* __restrict__ d2,
                                          float* __restrict__ sbv) {
  int blk = blockIdx.x, tid = threadIdx.x;
  if (blk < 16) {
    int e0 = blk * 2048 + tid * 8;     // 8 consecutive elems, same b
    float4 a0 = {0.f, 0.f, 0.f, 0.f}, a1 = {0.f, 0.f, 0.f, 0.f};
#pragma unroll
    for (int s = 0; s < 8; ++s) {
      const float* p = P2 + s * (BB * DD) + e0;
      float4 x = *(const float4*)p;
      float4 yv = *(const float4*)(p + 4);
      a0.x += x.x; a0.y += x.y; a0.z += x.z; a0.w += x.w;
      a1.x += yv.x; a1.y += yv.y; a1.z += yv.z; a1.w += yv.w;
    }
    short8 h = {(short)f2bf(a0.x), (short)f2bf(a0.y), (short)f2bf(a0.z),
                (short)f2bf(a0.w), (short)f2bf(a1.x), (short)f2bf(a1.y),
                (short)f2bf(a1.z), (short)f2bf(a1.w)};
    *(short8*)&zzbf[e0] = h;
    return;
  }
  __shared__ float u0l[DD];
  u0l[tid] = u0[tid];
  u0l[tid + 256] = u0[tid + 256];
  __syncthreads();
  int bl = tid >> 5, el = tid & 31;
  int b = (blk - 16) * 8 + bl;
  int yb = y[b];
  float acc = 0.f;
  for (int e = el; e < DD; e += 32)
    acc += (W_yemb[(size_t)e * NLBL + yb] + b_yemb[e]) * u0l[e];
#pragma unroll
  for (int d = 16; d; d >>= 1) acc += __shfl_down(acc, d, 32);
  if (el == 0) sbv[b] = acc + d2[0];
}

// ---------------- kC: direct GEMM out[b,l] = s[b]*dot(zz[b,:],W[l,:]) --------
// 256 blocks, l-tile 32 (l0 = blk*32), full K=512 in 4 chunks of 128.
// LDS 24 KB: As 64x128 bf16 (16 KB) + Bs 32x128 bf16 (8 KB), XOR-16-group
// swizzle phys_g = g ^ (row & 15)  -> conflict-free frag reads/writes.
// Wave w owns m-tile w (b = w*16+..); n-tiles 0,1 (l = l0 + ni*16 + l15).
__global__ __launch_bounds__(256) void kC(const unsigned short* __restrict__ zzbf,
                                          const float* __restrict__ W,
                                          const float* __restrict__ sbv,
                                          float* __restrict__ out) {
  __shared__ __align__(16) unsigned short As[64 * 128];
  __shared__ __align__(16) unsigned short Bs[32 * 128];
  int tid = threadIdx.x;
  int l0 = blockIdx.x * 32;
  int wave = tid >> 6, lane = tid & 63;
  int quad = lane >> 4, l15 = lane & 15;
  f32x4 acc[2] = {};
  for (int kc = 0; kc < 4; ++kc) {
    int k0 = kc * 128;
    // Bs: 32x128 bf16 from W fp32 (HBM), 512 slots, 2/thread
#pragma unroll
    for (int i = 0; i < 2; ++i) {
      int slot = tid + i * 256, row = slot >> 4, g = slot & 15;
      const float* src = &W[(size_t)(l0 + row) * DD + k0 + g * 8];
      float4 v0 = *(const float4*)src;
      float4 v1 = *(const float4*)(src + 4);
      short8 h = {(short)f2bf(v0.x), (short)f2bf(v0.y), (short)f2bf(v0.z),
                  (short)f2bf(v0.w), (short)f2bf(v1.x), (short)f2bf(v1.y),
                  (short)f2bf(v1.z), (short)f2bf(v1.w)};
      *(short8*)&Bs[row * 128 + ((g ^ (row & 15)) << 3)] = h;
    }
    // As: 64x128 bf16 from zzbf (L2-hot), 1024 slots, 4/thread
#pragma unroll
    for (int i = 0; i < 4; ++i) {
      int slot = tid + i * 256, row = slot >> 4, g = slot & 15;
      short8 h = *(const short8*)&zzbf[row * DD + k0 + g * 8];
      *(short8*)&As[row * 128 + ((g ^ (row & 15)) << 3)] = h;
    }
    __syncthreads();
#pragma unroll
    for (int s = 0; s < 4; ++s) {
      int g = s * 4 + quad;                      // k-group this lane reads
      short8 af = *(const short8*)&As[(wave * 16 + l15) * 128 +
                                      ((g ^ l15) << 3)];
#pragma unroll
      for (int ni = 0; ni < 2; ++ni) {
        short8 bf = *(const short8*)&Bs[(ni * 16 + l15) * 128 +
                                        ((g ^ l15) << 3)];
        acc[ni] = __builtin_amdgcn_mfma_f32_16x16x32_bf16(af, bf, acc[ni], 0, 0, 0);
      }
    }
    __syncthreads();
  }
  // epilogue: b = wave*16 + quad*4 + reg, l = l0 + ni*16 + l15
#pragma unroll
  for (int ni = 0; ni < 2; ++ni) {
#pragma unroll
    for (int reg = 0; reg < 4; ++reg) {
      int b = wave * 16 + quad * 4 + reg;
      out[(size_t)b * LL + l0 + ni * 16 + l15] = sbv[b] * acc[ni][reg];
    }
  }
}

extern "C" void kernel_launch(void* const* d_in, const int* in_sizes, int n_in,
                              void* d_out, int out_size, void* d_ws, size_t ws_size,
                              hipStream_t stream) {
  const float* z      = (const float*)d_in[0];
  const int*   y      = (const int*)  d_in[1];
  const float* W_yemb = (const float*)d_in[2];
  const float* b_yemb = (const float*)d_in[3];
  const float* Wy1    = (const float*)d_in[4];
  const float* by1    = (const float*)d_in[5];
  const float* Wy2    = (const float*)d_in[6];
  const float* by2    = (const float*)d_in[7];
  const float* Wz1    = (const float*)d_in[8];
  const float* bz1    = (const float*)d_in[9];
  const float* Wz2    = (const float*)d_in[10];
  const float* bz2    = (const float*)d_in[11];
  const float* W_zlat = (const float*)d_in[12];
  const float* w_proj = (const float*)d_in[13];

  float* ws = (float*)d_ws;
  float* P1 = ws;                        // [8][64][512] = 262144 floats
  float* P2 = ws + 262144;               // [8][64][512] = 262144 floats
  unsigned short* zzbf = (unsigned short*)(ws + 524288);   // [64][512] bf16
  float* u1 = ws + 524288 + 16384;       // [512]
  float* u0 = u1 + 512;                  // [512]
  float* sb = u0 + 512;                  // [64]
  float* d2 = sb + 64;                   // [1]
  float* out = (float*)d_out;

  kA<<<144, 256, 0, stream>>>(z, Wz1, bz1, P1, Wy2, w_proj, u1);
  kB<<<145, 256, 0, stream>>>(P1, Wz2, bz2, P2, Wy1, u1, u0, by1, by2, w_proj, d2);
  kZ<<<24, 256, 0, stream>>>(P2, zzbf, W_yemb, b_yemb, y, u0, d2, sb);
  kC<<<256, 256, 0, stream>>>(zzbf, W_zlat, sb, out);
}